// Round 12
// baseline (50.101 us; speedup 1.0000x reference)
//
#include <hip/hip_runtime.h>
#include <hip/hip_bf16.h>

#define N_ROWS 8192
#define DIM 128

typedef short v8s  __attribute__((ext_vector_type(8)));   // 8 bf16 (4 VGPRs) MFMA A/B frag
typedef float v16f __attribute__((ext_vector_type(16)));  // 32x32 MFMA C/D frag
typedef float v2f  __attribute__((ext_vector_type(2)));   // packed-f32 pair (v_pk_*)
typedef unsigned int u32;

constexpr int NS = 16;                // j-splits (blockIdx.y)
constexpr int CW = N_ROWS / NS;       // 512 j-rows per split
constexpr int NSLOT = NS;             // partial slots (one per j-split)
constexpr int TILE_J = 32;            // LDS-staged j-rows per tile
constexpr int NT = CW / TILE_J;       // 16 tiles per block
constexpr int TB = TILE_J * DIM * 2;  // 8 KB per buffer
constexpr int BI = 256;               // block i-width (4 waves x 64 cols)
constexpr int NRB = N_ROWS / 64;      // kreduce blocks (128)
constexpr float T2 = 0.0625f;         // THRESH^2: |pi-pj|<0.25 <=> d^2<0.0625
constexpr float C1 = 14.426950408889634f;  // 10*log2(e): exp(10*dot-10)=2^(C1*dot-C1)

// global->LDS async copy; size must be a literal (macro keeps it one).
#define GLDS(gptr, lptr, sz)                                                   \
  __builtin_amdgcn_global_load_lds(                                            \
      (const __attribute__((address_space(1))) u32*)(gptr),                    \
      (__attribute__((address_space(3))) u32*)(lptr), sz, 0, 0)

__device__ __forceinline__ unsigned short f2bf(float f) {
  __hip_bfloat16 h = __float2bfloat16(f);
  return __builtin_bit_cast(unsigned short, h);
}

// ---------------- kernel 1: L2-normalize rows, cast to bf16 ----------------
// Also re-initializes the kreduce ticket counter every call.
__global__ __launch_bounds__(256) void knorm(const float* __restrict__ emb,
                                             unsigned short* __restrict__ ebf,
                                             int* __restrict__ cnt) {
  if (blockIdx.x == 0 && threadIdx.x == 0) cnt[0] = 0;
  const int row  = blockIdx.x * 4 + (threadIdx.x >> 6);  // one wave per row
  const int lane = threadIdx.x & 63;
  const float2 v = *reinterpret_cast<const float2*>(emb + (size_t)row * DIM + lane * 2);
  float ss = fmaf(v.x, v.x, v.y * v.y);
#pragma unroll
  for (int off = 32; off > 0; off >>= 1) ss += __shfl_xor(ss, off);
  const float rn = 1.0f / sqrtf(ss);
  const unsigned int packed =
      (unsigned int)f2bf(v.x * rn) | ((unsigned int)f2bf(v.y * rn) << 16);
  *reinterpret_cast<unsigned int*>(ebf + (size_t)row * DIM + lane * 2) = packed;
}

// ---------------- kernel 2: fused sim-GEMM + row stats, register-blocked ----------------
// 4-wave blocks; each wave owns 64 i-cols: TWO persistent B-frag sets and two
// independent 8-MFMA chains sharing ONE af[8] LDS read. MFMA:ds_read = 2:1
// (was 1:1 — the unchanged variable across R6-R11's seven nulls; reference
// kernels that break the plateau run >=2:1 register-blocked ratios).
// LDS-read traffic per output halves. VGPR ~170 -> 2 waves/SIMD accepted:
// data is LDS-resident with 2-deep prefetch (not R3's global-latency regime).
// C/D layout (m74/m101): col = lane&31, row = (reg&3)+8*(reg>>2)+4*(lane>>5).
__global__ __launch_bounds__(256) void kmain(const unsigned short* __restrict__ ebf,
                                             const float* __restrict__ props,
                                             float* __restrict__ part) {
  const int tid  = threadIdx.x;
  const int lane = tid & 63;
  const int w    = tid >> 6;           // 0..3
  const int r31  = lane & 31;          // A-row / C-col index
  const int hi   = lane >> 5;          // 0..1
  const int i0   = blockIdx.x * BI;    // block i-range (256 cols)
  const int iw0  = i0 + w * 64;        // wave i-range (64 cols, 2 sets)
  const int jbase = blockIdx.y * CW;

  __shared__ __align__(1024) char sA[4 * TB + CW * 4];
  char* sprops = sA + 4 * TB;

  const int icolA = iw0 + r31;         // set-A output column
  const int icolB = iw0 + 32 + r31;    // set-B output column

  // persistent B-frags: frag kk holds e[icol][kk*16 + hi*8 .. +8)
  v8s bfrA[8], bfrB[8];
#pragma unroll
  for (int kk = 0; kk < 8; ++kk) {
    bfrA[kk] = *reinterpret_cast<const v8s*>(ebf + (size_t)icolA * DIM + kk * 16 + hi * 8);
    bfrB[kk] = *reinterpret_cast<const v8s*>(ebf + (size_t)icolB * DIM + kk * 16 + hi * 8);
  }
  const float pcA = props[icolA];
  const float pcB = props[icolB];

  // stage props[jbase .. +512) into LDS: two 4B GLDS per thread
#pragma unroll
  for (int r = 0; r < 2; ++r)
    GLDS(props + jbase + r * 256 + tid, sprops + r * 1024 + w * 256, 4);

  // stage one 32-row A-tile: two 16B GLDS per thread; LDS linear,
  // source pre-swizzled (LDS chunk s of row r holds global chunk s ^ (r&7))
  auto stageA = [&](char* base, int tile) {
    const int jrow0 = jbase + tile * TILE_J;
#pragma unroll
    for (int q = 0; q < 2; ++q) {
      const int row  = q * 16 + w * 4 + (lane >> 4);
      const int colb = ((lane & 15) << 4) ^ ((row & 7) << 4);
      GLDS(ebf + (size_t)(jrow0 + row) * DIM + (colb >> 1),
           base + q * 4096 + w * 1024, 16);
    }
  };

  v2f esA = {0.f, 0.f}, msA = {0.f, 0.f}, ctA = {0.f, 0.f};
  v2f esB = {0.f, 0.f}, msB = {0.f, 0.f}, ctB = {0.f, 0.f};
  const int rswz = (r31 & 7) << 4;     // read-side XOR swizzle
  const v2f c1v = {C1, C1}, mc1v = {-C1, -C1};
  const v2f pcA2 = {pcA, pcA}, pcB2 = {pcB, pcB};

  // compute one staged 32x32-j tile against both i-col sets
  auto compute = [&](const char* base, int tt) {
    const int jrow0 = jbase + tt * TILE_J;
    v8s af[8];
#pragma unroll
    for (int kk = 0; kk < 8; ++kk)
      af[kk] = *reinterpret_cast<const v8s*>(
          base + r31 * 256 + ((kk * 32 + hi * 16) ^ rswz));

    v16f accA = {0.f, 0.f, 0.f, 0.f, 0.f, 0.f, 0.f, 0.f,
                 0.f, 0.f, 0.f, 0.f, 0.f, 0.f, 0.f, 0.f};
    v16f accB = accA;
#pragma unroll
    for (int kk = 0; kk < 8; ++kk) {
      accA = __builtin_amdgcn_mfma_f32_32x32x16_bf16(af[kk], bfrA[kk], accA, 0, 0, 0);
      accB = __builtin_amdgcn_mfma_f32_32x32x16_bf16(af[kk], bfrB[kk], accB, 0, 0, 0);
    }

    if ((unsigned)(jrow0 - i0) < (unsigned)BI) {   // tile may contain the diagonal
#pragma unroll
      for (int r = 0; r < 8; ++r) {
        const int row0 = ((2 * r) & 3) + 8 * (r >> 1) + 4 * hi;  // rows row0, row0+1
        const v2f pj2  = *reinterpret_cast<const v2f*>(
            sprops + ((size_t)tt * 32 + row0) * 4);
        const int jr0 = jrow0 + row0;
        {
          const v2f dot2 = {accA[2 * r], accA[2 * r + 1]};
          const v2f arg  = __builtin_elementwise_fma(dot2, c1v, mc1v);
          const bool neq0 = (jr0 != icolA), neq1 = (jr0 + 1 != icolA);
          const v2f exv = {neq0 ? __builtin_amdgcn_exp2f(arg.x) : 0.f,
                           neq1 ? __builtin_amdgcn_exp2f(arg.y) : 0.f};
          esA += exv;
          const v2f d = pcA2 - pj2, dsq = d * d;
          const v2f msk = {(neq0 && dsq.x < T2) ? 1.f : 0.f,
                           (neq1 && dsq.y < T2) ? 1.f : 0.f};
          ctA += msk;
          msA = __builtin_elementwise_fma(msk, dot2, msA);
        }
        {
          const v2f dot2 = {accB[2 * r], accB[2 * r + 1]};
          const v2f arg  = __builtin_elementwise_fma(dot2, c1v, mc1v);
          const bool neq0 = (jr0 != icolB), neq1 = (jr0 + 1 != icolB);
          const v2f exv = {neq0 ? __builtin_amdgcn_exp2f(arg.x) : 0.f,
                           neq1 ? __builtin_amdgcn_exp2f(arg.y) : 0.f};
          esB += exv;
          const v2f d = pcB2 - pj2, dsq = d * d;
          const v2f msk = {(neq0 && dsq.x < T2) ? 1.f : 0.f,
                           (neq1 && dsq.y < T2) ? 1.f : 0.f};
          ctB += msk;
          msB = __builtin_elementwise_fma(msk, dot2, msB);
        }
      }
    } else {
#pragma unroll
      for (int r = 0; r < 8; ++r) {
        const int row0 = ((2 * r) & 3) + 8 * (r >> 1) + 4 * hi;
        const v2f pj2  = *reinterpret_cast<const v2f*>(
            sprops + ((size_t)tt * 32 + row0) * 4);
        {
          const v2f dot2 = {accA[2 * r], accA[2 * r + 1]};
          const v2f arg  = __builtin_elementwise_fma(dot2, c1v, mc1v);
          const v2f exv  = {__builtin_amdgcn_exp2f(arg.x), __builtin_amdgcn_exp2f(arg.y)};
          esA += exv;
          const v2f d = pcA2 - pj2, dsq = d * d;
          const v2f msk = {(dsq.x < T2) ? 1.f : 0.f, (dsq.y < T2) ? 1.f : 0.f};
          ctA += msk;
          msA = __builtin_elementwise_fma(msk, dot2, msA);
        }
        {
          const v2f dot2 = {accB[2 * r], accB[2 * r + 1]};
          const v2f arg  = __builtin_elementwise_fma(dot2, c1v, mc1v);
          const v2f exv  = {__builtin_amdgcn_exp2f(arg.x), __builtin_amdgcn_exp2f(arg.y)};
          esB += exv;
          const v2f d = pcB2 - pj2, dsq = d * d;
          const v2f msk = {(dsq.x < T2) ? 1.f : 0.f, (dsq.y < T2) ? 1.f : 0.f};
          ctB += msk;
          msB = __builtin_elementwise_fma(msk, dot2, msB);
        }
      }
    }
  };

  const int phase = (blockIdx.x * 5) & (NT - 1);       // convoy breaker
  stageA(sA + 0 * TB, phase);
  stageA(sA + 1 * TB, (phase + 1) & (NT - 1));
  __syncthreads();                     // tiles staged + props ready

  for (int t = 0; t < NT; t += 2) {
    const int tt0 = (t + phase) & (NT - 1);
    const int tt1 = (t + 1 + phase) & (NT - 1);
    if (t + 2 < NT) {
      stageA(sA + ((t + 2) & 3) * TB, (tt0 + 2) & (NT - 1));
      stageA(sA + ((t + 3) & 3) * TB, (tt1 + 2) & (NT - 1));
    }
    compute(sA + (t & 3) * TB, tt0);
    compute(sA + ((t + 1) & 3) * TB, tt1);
    __syncthreads();   // reads of t,t+1 done; stages for t+2,t+3 landed
  }

  // sum the two hi-halves (lanes l and l+32 hold complementary j-row subsets)
  float esa = esA.x + esA.y, msa = msA.x + msA.y, cta = ctA.x + ctA.y;
  float esb = esB.x + esB.y, msb = msB.x + msB.y, ctb = ctB.x + ctB.y;
  esa += __shfl_xor(esa, 32);  msa += __shfl_xor(msa, 32);  cta += __shfl_xor(cta, 32);
  esb += __shfl_xor(esb, 32);  msb += __shfl_xor(msb, 32);  ctb += __shfl_xor(ctb, 32);

  if (hi == 0) {
    float* p0 = part + (size_t)blockIdx.y * 3 * N_ROWS;  // slot = j-split; i disjoint per bx
    p0[icolA]              = esa;
    p0[N_ROWS + icolA]     = msa;
    p0[2 * N_ROWS + icolA] = cta;
    p0[icolB]              = esb;
    p0[N_ROWS + icolB]     = msb;
    p0[2 * N_ROWS + icolB] = ctb;
  }
}

// ---------------- kernel 3: per-row finalize + partials + last-block final ----------------
__global__ __launch_bounds__(64) void kreduce(const float* __restrict__ part,
                                              volatile float* __restrict__ bs,
                                              volatile float* __restrict__ bc,
                                              int* __restrict__ cnt,
                                              float* __restrict__ out) {
  const int row = blockIdx.x * 64 + threadIdx.x;
  float es = 0.f, ms = 0.f, ct = 0.f;
#pragma unroll
  for (int sp = 0; sp < NSLOT; ++sp) {
    const float* p0 = part + (size_t)sp * 3 * N_ROWS;
    es += p0[row];
    ms += p0[N_ROWS + row];
    ct += p0[2 * N_ROWS + row];
  }
  const float lse = 10.0f + logf(es);                       // logsumexp, M=10
  const float per = (ct * lse - 10.0f * ms) / fmaxf(ct, 1.0f);
  float val = (ct > 0.f) ? per : 0.f;
  float vld = (ct > 0.f) ? 1.f : 0.f;
#pragma unroll
  for (int off = 32; off > 0; off >>= 1) {
    val += __shfl_xor(val, off);
    vld += __shfl_xor(vld, off);
  }

  __shared__ int ticket;
  if (threadIdx.x == 0) {
    bs[blockIdx.x] = val;
    bc[blockIdx.x] = vld;
    __threadfence();                       // publish partials (device scope)
    ticket = atomicAdd(cnt, 1);            // device-scope ordering point
  }
  __syncthreads();
  if (ticket == NRB - 1) {                 // last block finalizes
    __threadfence();                       // acquire: see others' partials
    const int l = threadIdx.x;
    float s = bs[l] + bs[l + 64];
    float c = bc[l] + bc[l + 64];
#pragma unroll
    for (int off = 32; off > 0; off >>= 1) {
      s += __shfl_xor(s, off);
      c += __shfl_xor(c, off);
    }
    if (l == 0) out[0] = (c > 0.f) ? (s / c) : 0.f;
  }
}

extern "C" void kernel_launch(void* const* d_in, const int* in_sizes, int n_in,
                              void* d_out, int out_size, void* d_ws, size_t ws_size,
                              hipStream_t stream) {
  const float* emb   = (const float*)d_in[0];
  const float* props = (const float*)d_in[1];
  float* out = (float*)d_out;

  // ws layout: [0, 2MB) bf16 normalized embeddings; then NSLOT*3*N f32 partials;
  // then 128+128 f32 block partials; then ticket counter
  unsigned short* ebf = (unsigned short*)d_ws;
  const size_t EBF_BYTES  = (size_t)N_ROWS * DIM * 2;
  const size_t PART_BYTES = (size_t)NSLOT * 3 * N_ROWS * 4;
  float* part = (float*)((char*)d_ws + EBF_BYTES);
  float* bs   = (float*)((char*)d_ws + EBF_BYTES + PART_BYTES);
  float* bc   = bs + NRB;
  int*   cnt  = (int*)(bc + NRB);

  knorm<<<N_ROWS / 4, 256, 0, stream>>>(emb, ebf, cnt);
  kmain<<<dim3(N_ROWS / BI, NS), 256, 0, stream>>>(ebf, props, part);
  kreduce<<<NRB, 64, 0, stream>>>(part, bs, bc, cnt, out);
}